// Round 10
// baseline (207.115 us; speedup 1.0000x reference)
//
#include <hip/hip_runtime.h>
#include <hip/hip_bf16.h>
#include <cstdint>

// B=2, S=2048, E=1024, H=16, HD=64
#define SS 2048
#define EE 1024
#define HH 16
#define HDD 64

typedef __attribute__((ext_vector_type(8))) __bf16 bf16x8;
typedef __attribute__((ext_vector_type(4))) float f32x4;

#define MFMA16(a, b, c) __builtin_amdgcn_mfma_f32_16x16x32_bf16((a), (b), (c), 0, 0, 0)

__device__ __forceinline__ unsigned short f2bf(float f) {
    unsigned int u = __builtin_bit_cast(unsigned int, f);
    u += 0x7FFFu + ((u >> 16) & 1u);   // round-to-nearest-even
    return (unsigned short)(u >> 16);
}

// async global->LDS, 16B per lane; LDS dest is wave-uniform base + lane*16
__device__ __forceinline__ void gll16(const unsigned short* g, unsigned short* l) {
    __builtin_amdgcn_global_load_lds(
        (__attribute__((address_space(1))) unsigned int*)g,
        (__attribute__((address_space(3))) unsigned int*)l, 16, 0, 0);
}

// ---------------- fp32 -> bf16 convert (x + 4 weights) ----------------
__global__ __launch_bounds__(256) void cvt_all(
    const float* __restrict__ x, const float* __restrict__ wq, const float* __restrict__ wk,
    const float* __restrict__ wv, const float* __restrict__ wo,
    unsigned short* __restrict__ xb, unsigned short* __restrict__ wqb, unsigned short* __restrict__ wkb,
    unsigned short* __restrict__ wvb, unsigned short* __restrict__ wob) {
    int idx = blockIdx.x * 256 + threadIdx.x;
    int i4 = idx << 2;                       // 4 floats per thread
    const float* src;
    unsigned short* dst;
    int off;
    if (i4 < 4194304) { src = x; dst = xb; off = i4; }
    else {
        int w = (i4 - 4194304) >> 20;        // 0..3
        off = (i4 - 4194304) & 1048575;
        if (w == 0) { src = wq; dst = wqb; }
        else if (w == 1) { src = wk; dst = wkb; }
        else if (w == 2) { src = wv; dst = wvb; }
        else { src = wo; dst = wob; }
    }
    float4 v = *(const float4*)&src[off];
    unsigned int p0 = (unsigned int)f2bf(v.x) | ((unsigned int)f2bf(v.y) << 16);
    unsigned int p1 = (unsigned int)f2bf(v.z) | ((unsigned int)f2bf(v.w) << 16);
    uint2 u; u.x = p0; u.y = p1;
    *(uint2*)&dst[off] = u;
}

// ---------------- BT GEMM, DOUBLE-BUFFERED (one barrier per K-iter) ----------------
// BMTxBNT tile, BK=32, 256 threads (4 waves, 2x2). LDS passed in (hoisted) so
// template instantiations share the allocation (round-8 96KB lesson).
// Stage slab k+1 right after the barrier of iter k (round-7-proven).
// Tiles sized for blocks/CU: qkv 128x64 (grid 1536, ~4/CU), out 64x64 (grid
// 1024, 4/CU) — round-9 ledger showed both GEMMs grid-capped at 2-3 blocks/CU.
// MODE 0: bf16 out per-head [B,H,S,HD]  (Q)
// MODE 1: fp32 out [M,N]                (final projection)
// MODE 3: bf16 K in MFMA A-fragment order (HW-verified round 6)
// MODE 4: bf16 V in MFMA B-fragment order (HW-verified round 6)
template <int MODE, int BMT, int BNT>
__device__ __forceinline__ void gemm_core(
    unsigned short* __restrict__ lsA,        // [2][BMT*32]
    unsigned short* __restrict__ lsB,        // [2][BNT*32]
    const unsigned short* __restrict__ A, const unsigned short* __restrict__ W,
    const float* __restrict__ bias, void* __restrict__ out, int bm, int bn) {
    constexpr int IT = BMT / 32, JT = BNT / 32;
    constexpr int ASTR = BMT * 32, BSTR = BNT * 32;
    const int t = threadIdx.x;
    const int lane = t & 63, l15 = lane & 15, quad = lane >> 4;
    const int wave = t >> 6;
    const int wm = (wave >> 1) * (BMT / 2), wn = (wave & 1) * (BNT / 2);

    // staging: lane t -> physical chunk (t&3) of row (t>>2); load logical chunk (t&3)^((t>>3)&3)
    const int cg = ((t & 3) ^ ((t >> 3) & 3)) * 8;
    const unsigned short* ga = A + (size_t)(bm + (t >> 2)) * 1024 + cg;
    const unsigned short* gb = W + (size_t)(bn + (t >> 2)) * 1024 + cg;

    f32x4 acc[IT][JT];
    for (int i = 0; i < IT; i++)
        for (int j = 0; j < JT; j++) acc[i][j] = (f32x4){0.f, 0.f, 0.f, 0.f};

    const int swz = (l15 >> 1) & 3;  // (row>>1)&3 for row = wX + i*16 + l15

    // stage K-slab 0 into buffer 0
    gll16(ga, &lsA[t * 8]);
    if (BMT == 128) gll16(ga + 64 * 1024, &lsA[2048 + t * 8]);
    gll16(gb, &lsB[t * 8]);
    if (BNT == 128) gll16(gb + 64 * 1024, &lsB[2048 + t * 8]);

    for (int it = 0; it < 32; it++) {
        const int cur = it & 1, nxt = cur ^ 1;
        __syncthreads();  // cur staging done (issued a full body ago); prev reads of nxt drained

        if (it < 31) {
            const int k0 = (it + 1) * 32;
            gll16(ga + k0, &lsA[nxt * ASTR + t * 8]);
            if (BMT == 128) gll16(ga + k0 + 64 * 1024, &lsA[nxt * ASTR + 2048 + t * 8]);
            gll16(gb + k0, &lsB[nxt * BSTR + t * 8]);
            if (BNT == 128) gll16(gb + k0 + 64 * 1024, &lsB[nxt * BSTR + 2048 + t * 8]);
        }

        bf16x8 af[IT], bfr[JT];
        for (int i = 0; i < IT; i++)
            af[i] = *(const bf16x8*)&lsA[cur * ASTR + (wm + i * 16 + l15) * 32 + ((quad ^ swz) * 8)];
        for (int j = 0; j < JT; j++)
            bfr[j] = *(const bf16x8*)&lsB[cur * BSTR + (wn + j * 16 + l15) * 32 + ((quad ^ swz) * 8)];
        for (int i = 0; i < IT; i++)
            for (int j = 0; j < JT; j++) acc[i][j] = MFMA16(af[i], bfr[j], acc[i][j]);
    }

    // epilogue: C row = quad*4+reg, col = l15 per 16x16 tile (m89-verified)
    for (int j = 0; j < JT; j++) {
        int n = bn + wn + j * 16 + l15;
        float bj = bias[n];
        for (int i = 0; i < IT; i++) {
            int m0 = bm + wm + i * 16 + quad * 4;
            int srow0 = m0 & 2047, bidx = m0 >> 11;
            if (MODE == 3) {
                size_t headb = ((size_t)bidx * HH + (n >> 6)) * (SS * HDD);
                size_t base = headb + (size_t)(srow0 >> 6) * 4096 +
                              (size_t)(((srow0 >> 4) & 3) * 8 + ((n & 63) >> 3)) * 128 + (n & 7);
                for (int rg = 0; rg < 4; rg++)
                    ((unsigned short*)out)[base + (size_t)((srow0 & 15) + rg) * 8] = f2bf(acc[i][j][rg] + bj);
            } else if (MODE == 4) {
                size_t headb = ((size_t)bidx * HH + (n >> 6)) * (SS * HDD);
                size_t addr = headb + (size_t)(srow0 >> 6) * 4096 + (size_t)((n & 63) >> 4) * 1024 +
                              (size_t)(((srow0 >> 5) & 1) * 4 + ((srow0 >> 3) & 3)) * 128 +
                              (size_t)(n & 15) * 8 + (srow0 & 7);
                float v0 = acc[i][j][0] + bj, v1 = acc[i][j][1] + bj;
                float v2 = acc[i][j][2] + bj, v3 = acc[i][j][3] + bj;
                uint2 w;
                w.x = (unsigned int)f2bf(v0) | ((unsigned int)f2bf(v1) << 16);
                w.y = (unsigned int)f2bf(v2) | ((unsigned int)f2bf(v3) << 16);
                *(uint2*)&((unsigned short*)out)[addr] = w;
            } else {
                for (int rg = 0; rg < 4; rg++) {
                    float val = acc[i][j][rg] + bj;
                    int m = m0 + rg;
                    if (MODE == 0) {
                        ((unsigned short*)out)[(((size_t)(m >> 11) * HH + (n >> 6)) * SS + (m & 2047)) * HDD + (n & 63)] = f2bf(val);
                    } else {
                        ((float*)out)[(size_t)m * 1024 + n] = val;
                    }
                }
            }
        }
    }
}

// grid 1536 1-D (128x64 tiles, 32 by x 16 bx x 3 z); XCD swizzle: same-by blocks
// share an XCD (blk%8 = u for fixed by). launch_bounds(256,4): VGPR<=128 -> 4 blocks/CU.
__global__ __launch_bounds__(256, 4) void gemm_qkv(
    const unsigned short* __restrict__ xb,
    const unsigned short* __restrict__ wqb, const unsigned short* __restrict__ wkb,
    const unsigned short* __restrict__ wvb,
    const float* __restrict__ bq, const float* __restrict__ bk, const float* __restrict__ bv,
    unsigned short* qb, unsigned short* kb, unsigned short* vtb) {
    __shared__ unsigned short shA[2 * 4096];   // shared across all 3 instantiations
    __shared__ unsigned short shB[2 * 2048];
    const int blk = blockIdx.x;
    const int u = blk & 7, r = blk >> 3;      // r: 0..191
    const int by = u + 8 * (r & 3);           // 0..31
    const int rest = r >> 2;                  // 0..47
    const int bx = rest & 15;                 // 0..15
    const int z = rest >> 4;                  // 0..2
    if (z == 0)      gemm_core<0, 128, 64>(shA, shB, xb, wqb, bq, qb,  by * 128, bx * 64);
    else if (z == 1) gemm_core<3, 128, 64>(shA, shB, xb, wkb, bk, kb,  by * 128, bx * 64);
    else             gemm_core<4, 128, 64>(shA, shB, xb, wvb, bv, vtb, by * 128, bx * 64);
}

// grid 1024 1-D (64x64 tiles, 64 by x 16 bx) = 4 blocks/CU; same swizzle idea
__global__ __launch_bounds__(256, 4) void gemm_out(
    const unsigned short* __restrict__ ob, const unsigned short* __restrict__ wob,
    const float* __restrict__ bo, float* __restrict__ out) {
    __shared__ unsigned short shA[2 * 2048];
    __shared__ unsigned short shB[2 * 2048];
    const int blk = blockIdx.x;
    const int u = blk & 7, r = blk >> 3;      // r: 0..127
    const int by = u + 8 * (r & 7);           // 0..63
    const int bx = r >> 3;                    // 0..15
    gemm_core<1, 64, 64>(shA, shB, ob, wob, bo, out, by * 64, bx * 64);
}

// ---------------- flash attention: LDS double-buffer, ONE barrier/iter ----------------
// (unchanged from round 7/9 — stable at ~59 µs; grid-capped at 2 blocks/CU)
#define PSTR 72

__global__ __launch_bounds__(256) void attn_fwd(
    const unsigned short* __restrict__ qb, const unsigned short* __restrict__ kb,
    const unsigned short* __restrict__ vtb, unsigned short* __restrict__ ob) {
    __shared__ unsigned short lsK[2][4096];       // K fragment-order tiles (8 KB each)
    __shared__ unsigned short lsV[2][4096];       // V fragment-order tiles
    __shared__ unsigned short lsP[4 * 32 * PSTR]; // per-wave P [32 q][64 keys]
    const int t = threadIdx.x, lane = t & 63, l15 = lane & 15, quad = lane >> 4, wave = t >> 6;
    const int blk = blockIdx.x;
    const int u = blk & 7, r = blk >> 3;
    const int bh = u + 8 * (r & 3);   // 0..31: 4 heads per XCD
    const int qt = r >> 2;            // 0..15
    const size_t hoff = (size_t)bh * (SS * HDD);
    const float C = 0.125f * 1.44269504088896f;  // 1/sqrt(HD) * log2(e)

    // Q fragments in registers, pre-scaled by C (used as B-operand for S^T)
    bf16x8 qf[2][2];
    const int qrow = qt * 128 + wave * 32;
    for (int i = 0; i < 2; i++)
        for (int ks = 0; ks < 2; ks++) {
            bf16x8 raw = *(const bf16x8*)&qb[hoff + (size_t)(qrow + i * 16 + l15) * HDD + ks * 32 + quad * 8];
            unsigned short tmp[8];
            *(bf16x8*)tmp = raw;
            for (int j = 0; j < 8; j++) {
                float f = __builtin_bit_cast(float, (unsigned int)tmp[j] << 16);
                tmp[j] = f2bf(f * C);
            }
            qf[i][ks] = *(const bf16x8*)tmp;
        }

    unsigned short onesbuf[8];
    for (int j = 0; j < 8; j++) onesbuf[j] = 0x3F80;  // bf16 1.0
    const bf16x8 onesf = *(const bf16x8*)onesbuf;

    f32x4 lacc[2];                 // row-sums (denominator), C-layout rows
    f32x4 o[2][4];
    for (int i = 0; i < 2; i++) {
        lacc[i] = (f32x4){0.f, 0.f, 0.f, 0.f};
        for (int jh = 0; jh < 4; jh++) o[i][jh] = (f32x4){0.f, 0.f, 0.f, 0.f};
    }

    const unsigned short* gk = kb + hoff;   // + kt*4096, linear chunks
    const unsigned short* gv = vtb + hoff;
    const int pbase = wave * 32 * PSTR;
    const int foff = quad * 128 + l15 * 8;  // fragment offset within a tile

    // stage tile 0 into buffer 0
    gll16(gk + t * 8, &lsK[0][t * 8]);
    gll16(gk + 2048 + t * 8, &lsK[0][2048 + t * 8]);
    gll16(gv + t * 8, &lsV[0][t * 8]);
    gll16(gv + 2048 + t * 8, &lsV[0][2048 + t * 8]);

    for (int kt = 0; kt < 32; kt++) {
        const int cur = kt & 1, nxt = cur ^ 1;
        __syncthreads();  // cur staging done (issued a full body ago); prev reads of nxt drained

        // stage tile kt+1 into nxt (async; drained at next barrier)
        if (kt < 31) {
            const unsigned short* gkn = gk + (kt + 1) * 4096;
            const unsigned short* gvn = gv + (kt + 1) * 4096;
            gll16(gkn + t * 8, &lsK[nxt][t * 8]);
            gll16(gkn + 2048 + t * 8, &lsK[nxt][2048 + t * 8]);
            gll16(gvn + t * 8, &lsV[nxt][t * 8]);
            gll16(gvn + 2048 + t * 8, &lsV[nxt][2048 + t * 8]);
        }

        // K fragments from LDS (plain offsets, conflict-free)
        bf16x8 kfr[4][2];
        for (int j = 0; j < 4; j++)
            for (int ks = 0; ks < 2; ks++)
                kfr[j][ks] = *(const bf16x8*)&lsK[cur][j * 1024 + ks * 512 + foff];

        // S^T = K (CQ)^T : tile(j,i) rows = keys j*16+quad*4+rg, col = qrow i*16+l15
        f32x4 st[4][2];
        for (int j = 0; j < 4; j++)
            for (int i = 0; i < 2; i++) {
                f32x4 z = (f32x4){0.f, 0.f, 0.f, 0.f};
                z = MFMA16(kfr[j][0], qf[i][0], z);
                z = MFMA16(kfr[j][1], qf[i][1], z);
                st[j][i] = z;
            }

        // P = exp2(S^T) -> LDS [qrow][key], b64 writes (wave-private region)
        for (int j = 0; j < 4; j++)
            for (int i = 0; i < 2; i++) {
                float e0 = __builtin_amdgcn_exp2f(st[j][i][0]);
                float e1 = __builtin_amdgcn_exp2f(st[j][i][1]);
                float e2 = __builtin_amdgcn_exp2f(st[j][i][2]);
                float e3 = __builtin_amdgcn_exp2f(st[j][i][3]);
                uint2 w;
                w.x = (__builtin_bit_cast(unsigned int, e0) >> 16) |
                      (__builtin_bit_cast(unsigned int, e1) & 0xFFFF0000u);
                w.y = (__builtin_bit_cast(unsigned int, e2) >> 16) |
                      (__builtin_bit_cast(unsigned int, e3) & 0xFFFF0000u);
                *(uint2*)&lsP[pbase + (i * 16 + l15) * PSTR + j * 16 + quad * 4] = w;
            }

        // O += P V ; l += P . ones
        bf16x8 pf[2][2], vf[4][2];
        for (int i = 0; i < 2; i++)
            for (int ks = 0; ks < 2; ks++)
                pf[i][ks] = *(const bf16x8*)&lsP[pbase + (i * 16 + l15) * PSTR + ks * 32 + quad * 8];
        for (int jh = 0; jh < 4; jh++)
            for (int ks = 0; ks < 2; ks++)
                vf[jh][ks] = *(const bf16x8*)&lsV[cur][jh * 1024 + ks * 512 + foff];
        for (int i = 0; i < 2; i++) {
            for (int jh = 0; jh < 4; jh++) {
                o[i][jh] = MFMA16(pf[i][0], vf[jh][0], o[i][jh]);
                o[i][jh] = MFMA16(pf[i][1], vf[jh][1], o[i][jh]);
            }
            lacc[i] = MFMA16(pf[i][0], onesf, lacc[i]);
            lacc[i] = MFMA16(pf[i][1], onesf, lacc[i]);
        }
    }

    // epilogue: O / l -> bf16 in [B,S,E]
    const int b = bh >> 4, h = bh & 15;
    for (int i = 0; i < 2; i++)
        for (int rg = 0; rg < 4; rg++) {
            float inv = 1.f / lacc[i][rg];
            int srow = qt * 128 + wave * 32 + i * 16 + quad * 4 + rg;
            size_t rowoff = ((size_t)b * SS + srow) * EE + h * 64;
            for (int jh = 0; jh < 4; jh++)
                ob[rowoff + jh * 16 + l15] = f2bf(o[i][jh][rg] * inv);
        }
}

extern "C" void kernel_launch(void* const* d_in, const int* in_sizes, int n_in,
                              void* d_out, int out_size, void* d_ws, size_t ws_size,
                              hipStream_t stream) {
    const float* x  = (const float*)d_in[0];
    const float* wq = (const float*)d_in[1];
    const float* bq = (const float*)d_in[2];
    const float* wk = (const float*)d_in[3];
    const float* bk = (const float*)d_in[4];
    const float* wv = (const float*)d_in[5];
    const float* bv = (const float*)d_in[6];
    const float* wo = (const float*)d_in[7];
    const float* bo = (const float*)d_in[8];

    char* ws = (char*)d_ws;
    unsigned short* xb  = (unsigned short*)(ws + 0);          // 8 MB, reused as ob after qkv
    unsigned short* wqb = (unsigned short*)(ws + 8388608);    // 2 MB
    unsigned short* wkb = (unsigned short*)(ws + 10485760);
    unsigned short* wvb = (unsigned short*)(ws + 12582912);
    unsigned short* wob = (unsigned short*)(ws + 14680064);
    unsigned short* qb  = (unsigned short*)(ws + 16777216);   // 8 MB each
    unsigned short* kb  = (unsigned short*)(ws + 25165824);   // K in fragment order
    unsigned short* vtb = (unsigned short*)(ws + 33554432);   // V in fragment order
    unsigned short* ob  = xb;  // x no longer needed after qkv GEMM

    cvt_all<<<8192, 256, 0, stream>>>(x, wq, wk, wv, wo, xb, wqb, wkb, wvb, wob);
    gemm_qkv<<<1536, 256, 0, stream>>>(xb, wqb, wkb, wvb, bq, bk, bv, qb, kb, vtb);
    attn_fwd<<<512, 256, 0, stream>>>(qb, kb, vtb, ob);
    gemm_out<<<1024, 256, 0, stream>>>(ob, wob, bo, (float*)d_out);
}

// Round 11
// 190.540 us; speedup vs baseline: 1.0870x; 1.0870x over previous
//
#include <hip/hip_runtime.h>
#include <hip/hip_bf16.h>
#include <cstdint>

// B=2, S=2048, E=1024, H=16, HD=64
#define SS 2048
#define EE 1024
#define HH 16
#define HDD 64

typedef __attribute__((ext_vector_type(8))) __bf16 bf16x8;
typedef __attribute__((ext_vector_type(4))) float f32x4;

#define MFMA16(a, b, c) __builtin_amdgcn_mfma_f32_16x16x32_bf16((a), (b), (c), 0, 0, 0)

__device__ __forceinline__ unsigned short f2bf(float f) {
    unsigned int u = __builtin_bit_cast(unsigned int, f);
    u += 0x7FFFu + ((u >> 16) & 1u);   // round-to-nearest-even
    return (unsigned short)(u >> 16);
}

// async global->LDS, 16B per lane; LDS dest is wave-uniform base + lane*16
__device__ __forceinline__ void gll16(const unsigned short* g, unsigned short* l) {
    __builtin_amdgcn_global_load_lds(
        (__attribute__((address_space(1))) unsigned int*)g,
        (__attribute__((address_space(3))) unsigned int*)l, 16, 0, 0);
}

// ---------------- fp32 -> bf16 convert (x + 4 weights) ----------------
__global__ __launch_bounds__(256) void cvt_all(
    const float* __restrict__ x, const float* __restrict__ wq, const float* __restrict__ wk,
    const float* __restrict__ wv, const float* __restrict__ wo,
    unsigned short* __restrict__ xb, unsigned short* __restrict__ wqb, unsigned short* __restrict__ wkb,
    unsigned short* __restrict__ wvb, unsigned short* __restrict__ wob) {
    int idx = blockIdx.x * 256 + threadIdx.x;
    int i4 = idx << 2;                       // 4 floats per thread
    const float* src;
    unsigned short* dst;
    int off;
    if (i4 < 4194304) { src = x; dst = xb; off = i4; }
    else {
        int w = (i4 - 4194304) >> 20;        // 0..3
        off = (i4 - 4194304) & 1048575;
        if (w == 0) { src = wq; dst = wqb; }
        else if (w == 1) { src = wk; dst = wkb; }
        else if (w == 2) { src = wv; dst = wvb; }
        else { src = wo; dst = wob; }
    }
    float4 v = *(const float4*)&src[off];
    unsigned int p0 = (unsigned int)f2bf(v.x) | ((unsigned int)f2bf(v.y) << 16);
    unsigned int p1 = (unsigned int)f2bf(v.z) | ((unsigned int)f2bf(v.w) << 16);
    uint2 u; u.x = p0; u.y = p1;
    *(uint2*)&dst[off] = u;
}

// ---------------- BT GEMM, DOUBLE-BUFFERED (one barrier per K-iter) ----------------
// ROUND-9 CONFIG (best: qkv 128x128 grid 768, out 128x64 grid 512). Round-10's
// smaller tiles regressed (staging traffic x1.5 beat the TLP gain). LDS passed in
// (hoisted) so template instantiations share the allocation (round-8 96KB lesson).
// MODE 0: bf16 out per-head [B,H,S,HD]  (Q)
// MODE 1: fp32 out [M,N]                (final projection)
// MODE 3: bf16 K in MFMA A-fragment order (HW-verified round 6)
// MODE 4: bf16 V in MFMA B-fragment order (HW-verified round 6)
template <int MODE, int BMT, int BNT>
__device__ __forceinline__ void gemm_core(
    unsigned short* __restrict__ lsA,        // [2][BMT*32]
    unsigned short* __restrict__ lsB,        // [2][BNT*32]
    const unsigned short* __restrict__ A, const unsigned short* __restrict__ W,
    const float* __restrict__ bias, void* __restrict__ out, int bm, int bn) {
    constexpr int IT = BMT / 32, JT = BNT / 32;
    constexpr int ASTR = BMT * 32, BSTR = BNT * 32;
    const int t = threadIdx.x;
    const int lane = t & 63, l15 = lane & 15, quad = lane >> 4;
    const int wave = t >> 6;
    const int wm = (wave >> 1) * (BMT / 2), wn = (wave & 1) * (BNT / 2);

    // staging: lane t -> physical chunk (t&3) of row (t>>2); load logical chunk (t&3)^((t>>3)&3)
    const int cg = ((t & 3) ^ ((t >> 3) & 3)) * 8;
    const unsigned short* ga = A + (size_t)(bm + (t >> 2)) * 1024 + cg;
    const unsigned short* gb = W + (size_t)(bn + (t >> 2)) * 1024 + cg;

    f32x4 acc[IT][JT];
    for (int i = 0; i < IT; i++)
        for (int j = 0; j < JT; j++) acc[i][j] = (f32x4){0.f, 0.f, 0.f, 0.f};

    const int swz = (l15 >> 1) & 3;  // (row>>1)&3 for row = wX + i*16 + l15

    // stage K-slab 0 into buffer 0
    gll16(ga, &lsA[t * 8]);
    if (BMT == 128) gll16(ga + 64 * 1024, &lsA[2048 + t * 8]);
    gll16(gb, &lsB[t * 8]);
    if (BNT == 128) gll16(gb + 64 * 1024, &lsB[2048 + t * 8]);

    for (int it = 0; it < 32; it++) {
        const int cur = it & 1, nxt = cur ^ 1;
        __syncthreads();  // cur staging done (issued a full body ago); prev reads of nxt drained

        if (it < 31) {
            const int k0 = (it + 1) * 32;
            gll16(ga + k0, &lsA[nxt * ASTR + t * 8]);
            if (BMT == 128) gll16(ga + k0 + 64 * 1024, &lsA[nxt * ASTR + 2048 + t * 8]);
            gll16(gb + k0, &lsB[nxt * BSTR + t * 8]);
            if (BNT == 128) gll16(gb + k0 + 64 * 1024, &lsB[nxt * BSTR + 2048 + t * 8]);
        }

        bf16x8 af[IT], bfr[JT];
        for (int i = 0; i < IT; i++)
            af[i] = *(const bf16x8*)&lsA[cur * ASTR + (wm + i * 16 + l15) * 32 + ((quad ^ swz) * 8)];
        for (int j = 0; j < JT; j++)
            bfr[j] = *(const bf16x8*)&lsB[cur * BSTR + (wn + j * 16 + l15) * 32 + ((quad ^ swz) * 8)];
        for (int i = 0; i < IT; i++)
            for (int j = 0; j < JT; j++) acc[i][j] = MFMA16(af[i], bfr[j], acc[i][j]);
    }

    // epilogue: C row = quad*4+reg, col = l15 per 16x16 tile (m89-verified)
    for (int j = 0; j < JT; j++) {
        int n = bn + wn + j * 16 + l15;
        float bj = bias[n];
        for (int i = 0; i < IT; i++) {
            int m0 = bm + wm + i * 16 + quad * 4;
            int srow0 = m0 & 2047, bidx = m0 >> 11;
            if (MODE == 3) {
                size_t headb = ((size_t)bidx * HH + (n >> 6)) * (SS * HDD);
                size_t base = headb + (size_t)(srow0 >> 6) * 4096 +
                              (size_t)(((srow0 >> 4) & 3) * 8 + ((n & 63) >> 3)) * 128 + (n & 7);
                for (int rg = 0; rg < 4; rg++)
                    ((unsigned short*)out)[base + (size_t)((srow0 & 15) + rg) * 8] = f2bf(acc[i][j][rg] + bj);
            } else if (MODE == 4) {
                size_t headb = ((size_t)bidx * HH + (n >> 6)) * (SS * HDD);
                size_t addr = headb + (size_t)(srow0 >> 6) * 4096 + (size_t)((n & 63) >> 4) * 1024 +
                              (size_t)(((srow0 >> 5) & 1) * 4 + ((srow0 >> 3) & 3)) * 128 +
                              (size_t)(n & 15) * 8 + (srow0 & 7);
                float v0 = acc[i][j][0] + bj, v1 = acc[i][j][1] + bj;
                float v2 = acc[i][j][2] + bj, v3 = acc[i][j][3] + bj;
                uint2 w;
                w.x = (unsigned int)f2bf(v0) | ((unsigned int)f2bf(v1) << 16);
                w.y = (unsigned int)f2bf(v2) | ((unsigned int)f2bf(v3) << 16);
                *(uint2*)&((unsigned short*)out)[addr] = w;
            } else {
                for (int rg = 0; rg < 4; rg++) {
                    float val = acc[i][j][rg] + bj;
                    int m = m0 + rg;
                    if (MODE == 0) {
                        ((unsigned short*)out)[(((size_t)(m >> 11) * HH + (n >> 6)) * SS + (m & 2047)) * HDD + (n & 63)] = f2bf(val);
                    } else {
                        ((float*)out)[(size_t)m * 1024 + n] = val;
                    }
                }
            }
        }
    }
}

// grid 768 1-D (round-9 config); XCD swizzle: same-by blocks share an XCD
__global__ __launch_bounds__(256) void gemm_qkv(
    const unsigned short* __restrict__ xb,
    const unsigned short* __restrict__ wqb, const unsigned short* __restrict__ wkb,
    const unsigned short* __restrict__ wvb,
    const float* __restrict__ bq, const float* __restrict__ bk, const float* __restrict__ bv,
    unsigned short* qb, unsigned short* kb, unsigned short* vtb) {
    __shared__ unsigned short shA[2 * 4096];   // shared across all 3 instantiations
    __shared__ unsigned short shB[2 * 4096];
    const int blk = blockIdx.x;
    const int u = blk & 7, r = blk >> 3;
    const int by = u + 8 * (r & 3);          // 0..31
    const int rest = r >> 2;                 // 0..23
    const int bx = rest & 7, z = rest >> 3;  // 0..7, 0..2
    if (z == 0)      gemm_core<0, 128, 128>(shA, shB, xb, wqb, bq, qb,  by * 128, bx * 128);
    else if (z == 1) gemm_core<3, 128, 128>(shA, shB, xb, wkb, bk, kb,  by * 128, bx * 128);
    else             gemm_core<4, 128, 128>(shA, shB, xb, wvb, bv, vtb, by * 128, bx * 128);
}

// grid 512 1-D (round-9 config: 128x64 tiles)
__global__ __launch_bounds__(256) void gemm_out(
    const unsigned short* __restrict__ ob, const unsigned short* __restrict__ wob,
    const float* __restrict__ bo, float* __restrict__ out) {
    __shared__ unsigned short shA[2 * 4096];
    __shared__ unsigned short shB[2 * 2048];
    const int blk = blockIdx.x;
    const int u = blk & 7, r = blk >> 3;
    const int by = u + 8 * (r & 3);          // 0..31
    const int bx = r >> 2;                   // 0..15
    gemm_core<1, 128, 64>(shA, shB, ob, wob, bo, out, by * 128, bx * 64);
}

// ---------------- flash attention: INTRA-BLOCK SPLIT-K, 8 waves ----------------
// 512-thread blocks (8 waves): waves 0-3 process keys 0..1023, waves 4-7 keys
// 1024..2047; wave w and w^4 own the SAME 32 q-rows. Per-iter body identical to
// round-7 (same per-output economics — round-4's Q-halving lesson), 16 iters per
// wave, grid 512 -> 4 waves/SIMD (2x TLP on a latency-bound kernel).
// K/V single-buffered per half (16K+16K; dbuf won't fit 80KB/block), 2 barriers
// per iter (R5 cadence). lsP per-wave (PSTR=72). Final merge in LDS (fp32 exact):
// O = (N_A+N_B)/(l_A+l_B); combine buffers alias lsK/lsV/lsP (dead by then),
// element-major layout (lane-consecutive -> conflict-free).
#define PSTR 72

__global__ __launch_bounds__(512, 4) void attn_fwd(
    const unsigned short* __restrict__ qb, const unsigned short* __restrict__ kb,
    const unsigned short* __restrict__ vtb, unsigned short* __restrict__ ob) {
    __shared__ unsigned short sh[8192 + 8192 + 8 * 32 * PSTR];  // lsK[2][4096] | lsV[2][4096] | lsP[8][2304]
    unsigned short* lsK = sh;
    unsigned short* lsV = sh + 8192;
    unsigned short* lsP = sh + 16384;
    const int t = threadIdx.x, lane = t & 63, l15 = lane & 15, quad = lane >> 4;
    const int wave = t >> 6;          // 0..7
    const int half = wave >> 2;       // key-half
    const int wq = wave & 3;          // q-wave within half
    const int tg = t & 255;           // thread index within half-group
    const int blk = blockIdx.x;
    const int u = blk & 7, r = blk >> 3;
    const int bh = u + 8 * (r & 3);   // 0..31: 4 heads per XCD
    const int qt = r >> 2;            // 0..15
    const size_t hoff = (size_t)bh * (SS * HDD);
    const float C = 0.125f * 1.44269504088896f;  // 1/sqrt(HD) * log2(e)

    // Q fragments in registers, pre-scaled by C (used as B-operand for S^T)
    bf16x8 qf[2][2];
    const int qrow = qt * 128 + wq * 32;
    for (int i = 0; i < 2; i++)
        for (int ks = 0; ks < 2; ks++) {
            bf16x8 raw = *(const bf16x8*)&qb[hoff + (size_t)(qrow + i * 16 + l15) * HDD + ks * 32 + quad * 8];
            unsigned short tmp[8];
            *(bf16x8*)tmp = raw;
            for (int j = 0; j < 8; j++) {
                float f = __builtin_bit_cast(float, (unsigned int)tmp[j] << 16);
                tmp[j] = f2bf(f * C);
            }
            qf[i][ks] = *(const bf16x8*)tmp;
        }

    unsigned short onesbuf[8];
    for (int j = 0; j < 8; j++) onesbuf[j] = 0x3F80;  // bf16 1.0
    const bf16x8 onesf = *(const bf16x8*)onesbuf;

    f32x4 lacc[2];                 // row-sums (denominator), C-layout rows
    f32x4 o[2][4];
    for (int i = 0; i < 2; i++) {
        lacc[i] = (f32x4){0.f, 0.f, 0.f, 0.f};
        for (int jh = 0; jh < 4; jh++) o[i][jh] = (f32x4){0.f, 0.f, 0.f, 0.f};
    }

    // this half's 16 fragment-order tiles
    const unsigned short* gk = kb + hoff + (size_t)half * 16 * 4096;
    const unsigned short* gv = vtb + hoff + (size_t)half * 16 * 4096;
    unsigned short* myK = lsK + half * 4096;
    unsigned short* myV = lsV + half * 4096;
    const int pbase = wave * 32 * PSTR;
    const int foff = quad * 128 + l15 * 8;  // fragment offset within a tile

    // stage tile 0
    gll16(gk + tg * 8, myK + tg * 8);
    gll16(gk + 2048 + tg * 8, myK + 2048 + tg * 8);
    gll16(gv + tg * 8, myV + tg * 8);
    gll16(gv + 2048 + tg * 8, myV + 2048 + tg * 8);

    for (int kt = 0; kt < 16; kt++) {
        __syncthreads();  // staging drained (vmcnt(0) before s_barrier) & visible

        // K fragments from LDS (plain offsets, conflict-free)
        bf16x8 kfr[4][2];
        for (int j = 0; j < 4; j++)
            for (int ks = 0; ks < 2; ks++)
                kfr[j][ks] = *(const bf16x8*)&myK[j * 1024 + ks * 512 + foff];

        // S^T = K (CQ)^T : tile(j,i) rows = keys j*16+quad*4+rg, col = qrow i*16+l15
        f32x4 st[4][2];
        for (int j = 0; j < 4; j++)
            for (int i = 0; i < 2; i++) {
                f32x4 z = (f32x4){0.f, 0.f, 0.f, 0.f};
                z = MFMA16(kfr[j][0], qf[i][0], z);
                z = MFMA16(kfr[j][1], qf[i][1], z);
                st[j][i] = z;
            }

        // P = exp2(S^T) -> LDS [qrow][key], b64 writes (wave-private region)
        for (int j = 0; j < 4; j++)
            for (int i = 0; i < 2; i++) {
                float e0 = __builtin_amdgcn_exp2f(st[j][i][0]);
                float e1 = __builtin_amdgcn_exp2f(st[j][i][1]);
                float e2 = __builtin_amdgcn_exp2f(st[j][i][2]);
                float e3 = __builtin_amdgcn_exp2f(st[j][i][3]);
                uint2 w;
                w.x = (__builtin_bit_cast(unsigned int, e0) >> 16) |
                      (__builtin_bit_cast(unsigned int, e1) & 0xFFFF0000u);
                w.y = (__builtin_bit_cast(unsigned int, e2) >> 16) |
                      (__builtin_bit_cast(unsigned int, e3) & 0xFFFF0000u);
                *(uint2*)&lsP[pbase + (i * 16 + l15) * PSTR + j * 16 + quad * 4] = w;
            }

        // O += P V ; l += P . ones
        bf16x8 pf[2][2], vf[4][2];
        for (int i = 0; i < 2; i++)
            for (int ks = 0; ks < 2; ks++)
                pf[i][ks] = *(const bf16x8*)&lsP[pbase + (i * 16 + l15) * PSTR + ks * 32 + quad * 8];
        for (int jh = 0; jh < 4; jh++)
            for (int ks = 0; ks < 2; ks++)
                vf[jh][ks] = *(const bf16x8*)&myV[jh * 1024 + ks * 512 + foff];
        for (int i = 0; i < 2; i++) {
            for (int jh = 0; jh < 4; jh++) {
                o[i][jh] = MFMA16(pf[i][0], vf[jh][0], o[i][jh]);
                o[i][jh] = MFMA16(pf[i][1], vf[jh][1], o[i][jh]);
            }
            lacc[i] = MFMA16(pf[i][0], onesf, lacc[i]);
            lacc[i] = MFMA16(pf[i][1], onesf, lacc[i]);
        }

        if (kt < 15) {
            __syncthreads();  // all reads of current tile done before restage
            const unsigned short* gkn = gk + (kt + 1) * 4096;
            const unsigned short* gvn = gv + (kt + 1) * 4096;
            gll16(gkn + tg * 8, myK + tg * 8);
            gll16(gkn + 2048 + tg * 8, myK + 2048 + tg * 8);
            gll16(gvn + tg * 8, myV + tg * 8);
            gll16(gvn + 2048 + tg * 8, myV + 2048 + tg * 8);
        }
    }

    // ----- combine halves via LDS (fp32), then epilogue -----
    __syncthreads();  // all LDS reads done before alias overwrite
    float* cb = (float*)sh;           // N: [32 elems][4 wq][64 lanes], element-major (conflict-free)
    float* lb = cb + 8192;            // l: [8 elems][4 wq][64 lanes]
    const int lslot = wq * 64 + lane;
    if (half == 1) {
        for (int i = 0; i < 2; i++)
            for (int jh = 0; jh < 4; jh++)
                for (int rg = 0; rg < 4; rg++)
                    cb[(i * 16 + jh * 4 + rg) * 256 + lslot] = o[i][jh][rg];
        for (int i = 0; i < 2; i++)
            for (int rg = 0; rg < 4; rg++)
                lb[(i * 4 + rg) * 256 + lslot] = lacc[i][rg];
    }
    __syncthreads();
    if (half == 0) {
        const int b = bh >> 4, h = bh & 15;
        for (int i = 0; i < 2; i++)
            for (int rg = 0; rg < 4; rg++) {
                float inv = 1.f / (lacc[i][rg] + lb[(i * 4 + rg) * 256 + lslot]);
                int srow = qrow + i * 16 + quad * 4 + rg;
                size_t rowoff = ((size_t)b * SS + srow) * EE + h * 64;
                for (int jh = 0; jh < 4; jh++) {
                    float val = o[i][jh][rg] + cb[(i * 16 + jh * 4 + rg) * 256 + lslot];
                    ob[rowoff + jh * 16 + l15] = f2bf(val * inv);
                }
            }
    }
}

extern "C" void kernel_launch(void* const* d_in, const int* in_sizes, int n_in,
                              void* d_out, int out_size, void* d_ws, size_t ws_size,
                              hipStream_t stream) {
    const float* x  = (const float*)d_in[0];
    const float* wq = (const float*)d_in[1];
    const float* bq = (const float*)d_in[2];
    const float* wk = (const float*)d_in[3];
    const float* bk = (const float*)d_in[4];
    const float* wv = (const float*)d_in[5];
    const float* bv = (const float*)d_in[6];
    const float* wo = (const float*)d_in[7];
    const float* bo = (const float*)d_in[8];

    char* ws = (char*)d_ws;
    unsigned short* xb  = (unsigned short*)(ws + 0);          // 8 MB, reused as ob after qkv
    unsigned short* wqb = (unsigned short*)(ws + 8388608);    // 2 MB
    unsigned short* wkb = (unsigned short*)(ws + 10485760);
    unsigned short* wvb = (unsigned short*)(ws + 12582912);
    unsigned short* wob = (unsigned short*)(ws + 14680064);
    unsigned short* qb  = (unsigned short*)(ws + 16777216);   // 8 MB each
    unsigned short* kb  = (unsigned short*)(ws + 25165824);   // K in fragment order
    unsigned short* vtb = (unsigned short*)(ws + 33554432);   // V in fragment order
    unsigned short* ob  = xb;  // x no longer needed after qkv GEMM

    cvt_all<<<8192, 256, 0, stream>>>(x, wq, wk, wv, wo, xb, wqb, wkb, wvb, wob);
    gemm_qkv<<<768, 256, 0, stream>>>(xb, wqb, wkb, wvb, bq, bk, bv, qb, kb, vtb);
    attn_fwd<<<512, 512, 0, stream>>>(qb, kb, vtb, ob);
    gemm_out<<<512, 256, 0, stream>>>(ob, wob, bo, (float*)d_out);
}